// Round 8
// baseline (37030.820 us; speedup 1.0000x reference)
//
#include <hip/hip_runtime.h>

typedef _Float16 f16;
typedef _Float16 f16x8 __attribute__((ext_vector_type(8)));
typedef float f32x4 __attribute__((ext_vector_type(4)));

#define T_STEPS 1024
#define BATCH 128
#define HID 512
#define VOC 65
#define DRING 8
#define NLWG 96               // 3 layers * 32 dim-slices (batch-halves MERGED: 512-thr WGs)
#define NPWG 20               // 4 b-tiles * 5 v-tiles
#define FPAD 16               // ints per flag (64B line) — kills flag-line contention

// workspace layout (bytes) — identical to the proven round-0/5/6 kernel
// flags: layer (l*32+g)*FPAD  l=0..2 g=0..31 ; proj (96+p)*FPAD p=0..19
#define OFF_READY 0
#define OFF_HRING 32768
#define HRING_BYTES (3*DRING*BATCH*HID*2)            // 3,145,728
#define OFF_WPACK (OFF_HRING + HRING_BYTES)          // 3,178,496
#define WPACK_BYTES (3*32*65536*2)                   // 12,582,912
#define OFF_WOUT (OFF_WPACK + WPACK_BYTES)           // 15,761,408
#define WOUT_BYTES (5*16*512*2)                      // 81,920
#define OFF_EMB (OFF_WOUT + WOUT_BYTES)              // 15,843,328

// h-ring layout (transposed, proven r5): [l][slot][bh][d8(64)][row(64)][8 f16]
#define HHALF 32768           // f16 elements per (l,slot,bh)

__device__ __forceinline__ float sigmoidf_(float x){ return 1.0f/(1.0f+__expf(-x)); }
__device__ __forceinline__ float tanhf_(float x){ return 1.0f - 2.0f/(__expf(2.0f*x)+1.0f); }

// coherent 16B load: bypass L1+L2, read from coherence point (fresh cross-XCD data)
__device__ __forceinline__ f16x8 ld16_sc(const f16* p) {
  f16x8 r;
  asm volatile("global_load_dwordx4 %0, %1, off sc0 sc1" : "=v"(r) : "v"(p) : "memory");
  return r;
}
// plain cached 16B load (immutable data), asm so issue order/counting is pinned
__device__ __forceinline__ f16x8 ld16_pl(const f16* p) {
  f16x8 r;
  asm volatile("global_load_dwordx4 %0, %1, off" : "=v"(r) : "v"(p) : "memory");
  return r;
}
__device__ __forceinline__ void st16_sc1(f16* p, f16x8 v){
  asm volatile("global_store_dwordx4 %0, %1, off sc1"::"v"(p),"v"(v):"memory"); }

// Pack weights FRAG-MAJOR: per (layer l, slice g): 4 gate-tiles (r, z, n-hi, n-lo*2048)
// x 32 kc x [64 lanes x 8 f16] so a wave's ds_read_b128 is conflict-free. (unchanged)
__global__ void convert_kernel(const float* __restrict__ emb, const float* __restrict__ w_ih,
                               const float* __restrict__ w_hh, const float* __restrict__ w_out,
                               char* __restrict__ ws) {
  f16* wpack = (f16*)(ws + OFF_WPACK);
  f16* wout  = (f16*)(ws + OFF_WOUT);
  f16* embh  = (f16*)(ws + OFF_EMB);
  const int NW = 3*32*65536;
  const int TOT = NW + 40960 + VOC*HID;
  for (int e = blockIdx.x*blockDim.x + threadIdx.x; e < TOT; e += gridDim.x*blockDim.x) {
    if (e < NW) {
      int l = e >> 21, rem = e & 0x1FFFFF;
      int g = rem >> 16, idx = rem & 0xFFFF;
      int gt = idx >> 14, kc = (idx >> 9) & 31, lane = (idx >> 3) & 63, jj = idx & 7;
      int n = lane & 15, q = lane >> 4;
      int k = kc*32 + q*8 + jj, d = g*16 + n;
      int row = (gt==0) ? d : (gt==1) ? 512+d : 1024+d;
      float f = (k < 512) ? w_ih[((size_t)(l*1536+row)<<9) + k]
                          : w_hh[((size_t)(l*1536+row)<<9) + (k-512)];
      f16 h;
      if (gt < 3) h = (f16)f;
      else { f16 hi = (f16)f; h = (f16)((f - (float)hi)*2048.0f); }
      wpack[e] = h;
    } else if (e < NW + 40960) {
      int idx = e - NW;
      int vt = idx >> 13, r2 = idx & 8191;
      int kc = r2 >> 9, lane = (r2 >> 3) & 63, jj = r2 & 7;
      int n = lane & 15, q = lane >> 4;
      int v = vt*16 + n, k = kc*32 + q*8 + jj;
      wout[idx] = (v < VOC) ? (f16)w_out[((size_t)v<<9) + k] : (f16)0.0f;
    } else {
      int idx = e - NW - 40960;
      embh[idx] = (f16)emb[idx];
    }
  }
}

// keep-alive: pin 4 A-fragments so MFMAs can't hoist above the preceding vmcnt wait
#define KEEP4(K0) asm volatile("" : "+v"(afr[K0]), "+v"(afr[K0+1]), "+v"(afr[K0+2]), "+v"(afr[K0+3]))

// x-part chunk (kc in [K0,K0+4), K0 < 16)
#define XCHUNK(K0, NW_) \
  asm volatile("s_waitcnt vmcnt(" #NW_ ")" ::: "memory"); \
  KEEP4(K0); \
  _Pragma("unroll") \
  for (int kc = K0; kc < K0+4; ++kc) { \
    f16x8 wnh = *(const f16x8*)(wlds + (((2*32 + kc)*64 + lane) << 3)); \
    f16x8 wnl = *(const f16x8*)(wlds + (((3*32 + kc)*64 + lane) << 3)); \
    ar   = __builtin_amdgcn_mfma_f32_16x16x32_f16(afr[kc], wr[kc], ar,   0, 0, 0); \
    az   = __builtin_amdgcn_mfma_f32_16x16x32_f16(afr[kc], wz[kc], az,   0, 0, 0); \
    anxh = __builtin_amdgcn_mfma_f32_16x16x32_f16(afr[kc], wnh,    anxh, 0, 0, 0); \
    anxl = __builtin_amdgcn_mfma_f32_16x16x32_f16(afr[kc], wnl,    anxl, 0, 0, 0); \
  }

// h-part chunk (kc in [K0,K0+4), K0 >= 16)
#define HCHUNK(K0, NW_) \
  asm volatile("s_waitcnt vmcnt(" #NW_ ")" ::: "memory"); \
  KEEP4(K0); \
  _Pragma("unroll") \
  for (int kc = K0; kc < K0+4; ++kc) { \
    f16x8 wnh = *(const f16x8*)(wlds + (((2*32 + kc)*64 + lane) << 3)); \
    f16x8 wnl = *(const f16x8*)(wlds + (((3*32 + kc)*64 + lane) << 3)); \
    ar   = __builtin_amdgcn_mfma_f32_16x16x32_f16(afr[kc], wr[kc], ar,   0, 0, 0); \
    az   = __builtin_amdgcn_mfma_f32_16x16x32_f16(afr[kc], wz[kc], az,   0, 0, 0); \
    anhh = __builtin_amdgcn_mfma_f32_16x16x32_f16(afr[kc], wnh,    anhh, 0, 0, 0); \
    anhl = __builtin_amdgcn_mfma_f32_16x16x32_f16(afr[kc], wnl,    anhl, 0, 0, 0); \
  }

// Persistent kernel, 116 WGs x 512 threads — r6 protocol with batch-halves MERGED per WG:
// wave wv (0..7) owns batch rows [16wv,16wv+16); same per-thread code as the proven r6 kernel
// but 8 waves/CU (2x outstanding loads per CU). Flags: one per (layer, dim-slice).
__global__ void __launch_bounds__(512) rnn_kernel(const int* __restrict__ xseq,
                           const float* __restrict__ bias, const float* __restrict__ bias_n,
                           const float* __restrict__ b_out, float* __restrict__ out,
                           char* __restrict__ ws) {
  int* F = (int*)(ws + OFF_READY);
  f16* hring = (f16*)(ws + OFF_HRING);                // [3][8][2][64][64][8] transposed
  const int wg = blockIdx.x;
  const int tid = threadIdx.x;
  const int lane = tid & 63, wv = tid >> 6;           // wv 0..7
  const int quad = lane >> 4, nlane = lane & 15;

  __shared__ __align__(16) f16 wlds[65536];           // 131,072 B
  __shared__ __align__(16) f16 wolds[8192];           // 16,384 B
  __shared__ __align__(16) f16 hstage[128*24];        // 6,144 B (stride 24 f16 rows)

  if (wg < NLWG) {
    const int l = wg >> 5, g = wg & 31;
    {
      const f16x8* src = (const f16x8*)((const f16*)(ws + OFF_WPACK) + ((size_t)(l*32+g) << 16));
      f16x8* dst = (f16x8*)wlds;
      for (int i = tid; i < 8192; i += 512) dst[i] = src[i];
    }
    const int j = g*16 + nlane;
    const float br  = bias[l*1536 + j];
    const float bz  = bias[l*1536 + 512 + j];
    const float bin = bias[l*1536 + 1024 + j];
    const float bn  = bias_n[l*512 + j];
    const int bm = wv*16 + nlane;                     // absolute batch row 0..127
    const int bhsel = wv >> 2;                        // which bh-half this wave's rows live in
    // per-lane offset into a transposed (l,slot,bh) half: [d8=kc*4+quad][row64][8]
    const int tofs = quad*512 + (((wv & 3)*16) + nlane)*8;   // + kc*2048 per kc

    // poll pointers: wave0 = self (lanes<32) + upstream (lanes>=32); wave1 = back-pressure
    const int* selfp = F + (l*32 + (lane & 31))*FPAD;
    const int* upp   = (l > 0) ? (F + ((l-1)*32 + (lane & 31))*FPAD) : F;
    const int* bpp = F; int bpact = 0;
    if (wv == 1) {
      if (l < 2) { if (lane < 32) { bpp = F + ((l+1)*32 + lane)*FPAD; bpact = 1; } }
      else       { if (lane < 20) { bpp = F + (96 + lane)*FPAD;       bpact = 1; } }
    }
    __syncthreads();
    // register-resident B-frags for r and z gates; conflict-free reads
    f16x8 wr[32], wz[32];
#pragma unroll
    for (int kc = 0; kc < 32; ++kc) {
      wr[kc] = *(const f16x8*)(wlds + (((0*32 + kc)*64 + lane) << 3));
      wz[kc] = *(const f16x8*)(wlds + (((1*32 + kc)*64 + lane) << 3));
    }
    const f16* embh = (const f16*)(ws + OFF_EMB);
    unsigned short hprev[4] = {0, 0, 0, 0};           // h(t-1) for this thread's (row, col) — f16 bits

    for (int t = 0; t < T_STEPS; ++t) {
      // ---- phase A: upstream readiness (x-input) + downstream back-pressure ----
      if (wv == 0) {
        if (l > 0 && lane >= 32) {
          const int tgt = t + 1;
          int spins = 0;
          while (1) {
            int v = __hip_atomic_load(upp, __ATOMIC_RELAXED, __HIP_MEMORY_SCOPE_AGENT);
            if (__all(v >= tgt)) break;
            if (++spins > (1 << 22)) break;           // hang-safety: fail visibly, not forever
            __builtin_amdgcn_s_sleep(1);
          }
        }
      } else if (wv == 1) {
        const int tgt = t - (DRING-1);
        int spins = 0;
        while (1) {
          int v = 0x7FFFFFFF;
          if (bpact) v = __hip_atomic_load(bpp, __ATOMIC_RELAXED, __HIP_MEMORY_SCOPE_AGENT);
          if (__all(v >= tgt)) break;
          if (++spins > (1 << 22)) break;
          __builtin_amdgcn_s_sleep(1);
        }
      }
      __syncthreads();                                // B1: x-input ready

      const int slot_w = t & (DRING-1), slot_r = (t + DRING - 1) & (DRING-1);
      f16x8 afr[32];
      // issue x loads (no wait) — they fly during the self-poll
      if (l == 0) {
        int idx = xseq[bm*T_STEPS + t];
        const f16* xr = embh + (size_t)idx*HID + quad*8;   // immutable: plain cached loads
#pragma unroll
        for (int kc = 0; kc < 16; ++kc) afr[kc] = ld16_pl(xr + kc*32);
      } else {
        const f16* xr = hring + (size_t)(((l-1)*DRING + slot_w)*2 + bhsel)*HHALF + tofs;
#pragma unroll
        for (int kc = 0; kc < 16; ++kc) afr[kc] = ld16_sc(xr + kc*2048);
      }
      // ---- phase B: self h(t-1) readiness, overlapped with x-load flight ----
      if (wv == 0 && lane < 32) {
        int spins = 0;
        while (1) {
          int v = __hip_atomic_load(selfp, __ATOMIC_RELAXED, __HIP_MEMORY_SCOPE_AGENT);
          if (__all(v >= t)) break;
          if (++spins > (1 << 22)) break;
          __builtin_amdgcn_s_sleep(1);
        }
      }
      __syncthreads();                                // B2: self h(t-1) visible
      // issue h loads (no wait) — they fly during the x-GEMM
      {
        const f16* hrk = hring + (size_t)((l*DRING + slot_r)*2 + bhsel)*HHALF + tofs;
#pragma unroll
        for (int kc = 0; kc < 16; ++kc) afr[16 + kc] = ld16_sc(hrk + kc*2048);
      }

      f32x4 ar{0,0,0,0}, az{0,0,0,0}, anxh{0,0,0,0}, anxl{0,0,0,0}, anhh{0,0,0,0}, anhl{0,0,0,0};
      XCHUNK(0, 28)  XCHUNK(4, 24)  XCHUNK(8, 20)   XCHUNK(12, 16)
      HCHUNK(16, 12) HCHUNK(20, 8)  HCHUNK(24, 4)   HCHUNK(28, 0)

      // epilogue: D layout col(lane&15)=dim j, row(wv*16+quad*4+i)=absolute batch row
#pragma unroll
      for (int i = 0; i < 4; ++i) {
        float rr = sigmoidf_(ar[i] + br);
        float zz = sigmoidf_(az[i] + bz);
        float hn = anhh[i] + anhl[i]*(1.0f/2048.0f) + bn;
        float nn = tanhf_(anxh[i] + anxl[i]*(1.0f/2048.0f) + bin + rr*hn);
        union { unsigned short u; f16 h; } cr; cr.u = hprev[i];
        float hv = nn + zz*((float)cr.h - nn);
        union { f16 h; unsigned short u; } cw; cw.h = (f16)hv;
        hprev[i] = cw.u;
        hstage[(wv*16 + quad*4 + i)*24 + nlane] = cw.h;   // LDS transpose stage
      }
      __syncthreads();
      // h stores, transposed layout: 256 threads -> four 1KB contiguous chunks (full lines)
      if (tid < 256) {
        int d8i = tid >> 7, row_abs = tid & 127;
        int bh2 = row_abs >> 6, r64 = row_abs & 63;
        f16x8 v8 = *(const f16x8*)(hstage + row_abs*24 + d8i*8);
        f16* hw = hring + (size_t)((l*DRING + slot_w)*2 + bh2)*HHALF
                        + (size_t)(2*g + d8i)*512 + r64*8;
        st16_sc1(hw, v8);
      }
      asm volatile("s_waitcnt vmcnt(0)" ::: "memory"); // sc1 stores reached coherence point
      __syncthreads();
      if (tid == 0)
        __hip_atomic_store(F + (l*32 + g)*FPAD, t + 1,
                           __ATOMIC_RELAXED, __HIP_MEMORY_SCOPE_AGENT);
    }
  } else if (wg < NLWG + NPWG) {
    const int p = wg - NLWG, bt = p / 5, vt = p % 5;
    {
      const f16x8* src = (const f16x8*)((const f16*)(ws + OFF_WOUT) + vt*8192);
      f16x8* dst = (f16x8*)wolds;
      for (int i = tid; i < 1024; i += 512) dst[i] = src[i];
    }
    const int v = vt*16 + nlane;
    const float bo = (v < VOC) ? b_out[v] : 0.0f;
    __syncthreads();
    for (int t = 0; t < T_STEPS; ++t) {
      if (wv == 0) {
        const int tgt = t + 1;
        int spins = 0;
        while (1) {
          int vv = 0x7FFFFFFF;
          if (lane < 32) vv = __hip_atomic_load(F + (2*32 + lane)*FPAD,
                                                __ATOMIC_RELAXED, __HIP_MEMORY_SCOPE_AGENT);
          if (__all(vv >= tgt)) break;
          if (++spins > (1 << 22)) break;
          __builtin_amdgcn_s_sleep(1);
        }
      }
      __syncthreads();
      if (wv < 2) {
        const int row_abs = bt*32 + wv*16 + nlane;     // absolute batch row 0..127
        const int bh2 = row_abs >> 6, rih = row_abs & 63;
        const f16* hrow = hring + (size_t)((2*DRING + (t & (DRING-1)))*2 + bh2)*HHALF
                                + quad*512 + rih*8;
        f16x8 af[16];
#pragma unroll
        for (int kc = 0; kc < 16; ++kc) af[kc] = ld16_sc(hrow + kc*2048);
        asm volatile("s_waitcnt vmcnt(0)" ::: "memory");
#pragma unroll
        for (int kc = 0; kc < 16; ++kc) asm volatile("" : "+v"(af[kc]));
        f32x4 acc{0,0,0,0};
#pragma unroll
        for (int kc = 0; kc < 16; ++kc) {
          f16x8 w = *(const f16x8*)(wolds + ((kc*64 + lane) << 3));
          acc = __builtin_amdgcn_mfma_f32_16x16x32_f16(af[kc], w, acc, 0, 0, 0);
        }
        if (v < VOC) {
          const int bmb = bt*32 + wv*16;
#pragma unroll
          for (int i = 0; i < 4; ++i) {
            int bidx = bmb + quad*4 + i;
            out[((size_t)bidx*T_STEPS + t)*VOC + v] = acc[i] + bo;
          }
        }
      }
      __syncthreads();
      if (tid == 0)
        __hip_atomic_store(F + (96 + p)*FPAD, t + 1, __ATOMIC_RELAXED, __HIP_MEMORY_SCOPE_AGENT);
    }
  }
}

extern "C" void kernel_launch(void* const* d_in, const int* in_sizes, int n_in,
                              void* d_out, int out_size, void* d_ws, size_t ws_size,
                              hipStream_t stream) {
  const int*   xseq  = (const int*)d_in[0];
  const float* emb   = (const float*)d_in[1];
  const float* w_ih  = (const float*)d_in[2];
  const float* w_hh  = (const float*)d_in[3];
  const float* b     = (const float*)d_in[4];
  const float* b_n   = (const float*)d_in[5];
  const float* w_out = (const float*)d_in[6];
  const float* b_out = (const float*)d_in[7];
  char* ws = (char*)d_ws;

  // zero flags + h ring (h[-1] = 0 initial state); re-done every call
  (void)hipMemsetAsync(d_ws, 0, OFF_HRING + HRING_BYTES, stream);
  hipLaunchKernelGGL(convert_kernel, dim3(4096), dim3(256), 0, stream,
                     emb, w_ih, w_hh, w_out, ws);
  hipLaunchKernelGGL(rnn_kernel, dim3(NLWG + NPWG), dim3(512), 0, stream,
                     xseq, b, b_n, b_out, (float*)d_out, ws);
}

// Round 9
// 10101.084 us; speedup vs baseline: 3.6660x; 3.6660x over previous
//
#include <hip/hip_runtime.h>

typedef _Float16 f16;
typedef _Float16 f16x8 __attribute__((ext_vector_type(8)));
typedef float f32x4 __attribute__((ext_vector_type(4)));

#define T_STEPS 1024
#define BATCH 128
#define HID 512
#define VOC 65
#define DRING 8
#define FPAD 16               // ints per flag (64B line)

// ---- workspace layout (bytes) — footprint identical to proven r6 ----
#define OFF_READY 0           // FC flags: (l*64+bh*32+g)*FPAD ; proj FP at (192+p)*FPAD
#define OFF_FL    16384       // FL local flags: (l*64+bh*32+g)*FPAD (plain store / sc0 load)
#define OFF_CTL   28672       // TS[6][64], VT[6][32], MD[6]
#define OFF_HRING 32768
#define HRING_BYTES (3*DRING*BATCH*HID*2)            // 3,145,728
#define OFF_WPACK (OFF_HRING + HRING_BYTES)          // 3,178,496
#define WPACK_BYTES (3*32*65536*2)                   // 12,582,912
#define OFF_WOUT (OFF_WPACK + WPACK_BYTES)           // 15,761,408
#define WOUT_BYTES (5*16*512*2)                      // 81,920
#define OFF_EMB (OFF_WOUT + WOUT_BYTES)              // 15,843,328

// h-ring layout (transposed, proven r5): [l][slot][bh][d8(64)][row(64)][8 f16]
#define HHALF 32768

__device__ __forceinline__ float sigmoidf_(float x){ return 1.0f/(1.0f+__expf(-x)); }
__device__ __forceinline__ float tanhf_(float x){ return 1.0f - 2.0f/(__expf(2.0f*x)+1.0f); }

// coherence-point ops
__device__ __forceinline__ f16x8 ld16_sc(const f16* p) {
  f16x8 r;
  asm volatile("global_load_dwordx4 %0, %1, off sc0 sc1" : "=v"(r) : "v"(p) : "memory");
  return r;
}
__device__ __forceinline__ void st16_sc1(f16* p, f16x8 v){
  asm volatile("global_store_dwordx4 %0, %1, off sc1"::"v"(p),"v"(v):"memory"); }
// plain cached 16B (immutable data / local-L2 write-back)
__device__ __forceinline__ f16x8 ld16_pl(const f16* p) {
  f16x8 r;
  asm volatile("global_load_dwordx4 %0, %1, off" : "=v"(r) : "v"(p) : "memory");
  return r;
}
__device__ __forceinline__ void st16_pl(f16* p, f16x8 v){
  asm volatile("global_store_dwordx4 %0, %1, off"::"v"(p),"v"(v):"memory"); }
// sc0 16B: L1 bypass, L2 allowed (same-XCD reads of plain-stored dirty lines)
__device__ __forceinline__ f16x8 ld16_l2(const f16* p) {
  f16x8 r;
  asm volatile("global_load_dwordx4 %0, %1, off sc0" : "=v"(r) : "v"(p) : "memory");
  return r;
}
// flag ops
__device__ __forceinline__ int ld4_sc(const int* p){
  int r;
  asm volatile("global_load_dword %0, %1, off sc0 sc1\n\ts_waitcnt vmcnt(0)" : "=v"(r) : "v"(p) : "memory");
  return r;
}
__device__ __forceinline__ int ld4_l2(const int* p){
  int r;
  asm volatile("global_load_dword %0, %1, off sc0\n\ts_waitcnt vmcnt(0)" : "=v"(r) : "v"(p) : "memory");
  return r;
}
__device__ __forceinline__ void st4_sc1(int* p, int v){
  asm volatile("global_store_dword %0, %1, off sc1"::"v"(p),"v"(v):"memory"); }
__device__ __forceinline__ void st4_pl(int* p, int v){
  asm volatile("global_store_dword %0, %1, off"::"v"(p),"v"(v):"memory"); }

// Pack weights FRAG-MAJOR (unchanged, proven).
__global__ void convert_kernel(const float* __restrict__ emb, const float* __restrict__ w_ih,
                               const float* __restrict__ w_hh, const float* __restrict__ w_out,
                               char* __restrict__ ws) {
  f16* wpack = (f16*)(ws + OFF_WPACK);
  f16* wout  = (f16*)(ws + OFF_WOUT);
  f16* embh  = (f16*)(ws + OFF_EMB);
  const int NW = 3*32*65536;
  const int TOT = NW + 40960 + VOC*HID;
  for (int e = blockIdx.x*blockDim.x + threadIdx.x; e < TOT; e += gridDim.x*blockDim.x) {
    if (e < NW) {
      int l = e >> 21, rem = e & 0x1FFFFF;
      int g = rem >> 16, idx = rem & 0xFFFF;
      int gt = idx >> 14, kc = (idx >> 9) & 31, lane = (idx >> 3) & 63, jj = idx & 7;
      int n = lane & 15, q = lane >> 4;
      int k = kc*32 + q*8 + jj, d = g*16 + n;
      int row = (gt==0) ? d : (gt==1) ? 512+d : 1024+d;
      float f = (k < 512) ? w_ih[((size_t)(l*1536+row)<<9) + k]
                          : w_hh[((size_t)(l*1536+row)<<9) + (k-512)];
      f16 h;
      if (gt < 3) h = (f16)f;
      else { f16 hi = (f16)f; h = (f16)((f - (float)hi)*2048.0f); }
      wpack[e] = h;
    } else if (e < NW + 40960) {
      int idx = e - NW;
      int vt = idx >> 13, r2 = idx & 8191;
      int kc = r2 >> 9, lane = (r2 >> 3) & 63, jj = r2 & 7;
      int n = lane & 15, q = lane >> 4;
      int v = vt*16 + n, k = kc*32 + q*8 + jj;
      wout[idx] = (v < VOC) ? (f16)w_out[((size_t)v<<9) + k] : (f16)0.0f;
    } else {
      int idx = e - NW - 40960;
      embh[idx] = (f16)emb[idx];
    }
  }
}

#define KEEP4(K0) asm volatile("" : "+v"(afr[K0]), "+v"(afr[K0+1]), "+v"(afr[K0+2]), "+v"(afr[K0+3]))

#define XCHUNK(K0, NW_) \
  asm volatile("s_waitcnt vmcnt(" #NW_ ")" ::: "memory"); \
  KEEP4(K0); \
  _Pragma("unroll") \
  for (int kc = K0; kc < K0+4; ++kc) { \
    f16x8 wnh = *(const f16x8*)(wlds + (((2*32 + kc)*64 + lane) << 3)); \
    f16x8 wnl = *(const f16x8*)(wlds + (((3*32 + kc)*64 + lane) << 3)); \
    ar   = __builtin_amdgcn_mfma_f32_16x16x32_f16(afr[kc], wr[kc], ar,   0, 0, 0); \
    az   = __builtin_amdgcn_mfma_f32_16x16x32_f16(afr[kc], wz[kc], az,   0, 0, 0); \
    anxh = __builtin_amdgcn_mfma_f32_16x16x32_f16(afr[kc], wnh,    anxh, 0, 0, 0); \
    anxl = __builtin_amdgcn_mfma_f32_16x16x32_f16(afr[kc], wnl,    anxl, 0, 0, 0); \
  }

#define HCHUNK(K0, NW_) \
  asm volatile("s_waitcnt vmcnt(" #NW_ ")" ::: "memory"); \
  KEEP4(K0); \
  _Pragma("unroll") \
  for (int kc = K0; kc < K0+4; ++kc) { \
    f16x8 wnh = *(const f16x8*)(wlds + (((2*32 + kc)*64 + lane) << 3)); \
    f16x8 wnl = *(const f16x8*)(wlds + (((3*32 + kc)*64 + lane) << 3)); \
    ar   = __builtin_amdgcn_mfma_f32_16x16x32_f16(afr[kc], wr[kc], ar,   0, 0, 0); \
    az   = __builtin_amdgcn_mfma_f32_16x16x32_f16(afr[kc], wz[kc], az,   0, 0, 0); \
    anhh = __builtin_amdgcn_mfma_f32_16x16x32_f16(afr[kc], wnh,    anhh, 0, 0, 0); \
    anhl = __builtin_amdgcn_mfma_f32_16x16x32_f16(afr[kc], wnl,    anhl, 0, 0, 0); \
  }

// Persistent kernel, 256 WGs x 256 threads. Roles: xcd=blockIdx&7 (0..5 layer group gid,
// member g=blockIdx>>3; 6: proj p=blockIdx>>3 (<20); 7+spares: exit).
// SLOW = exact r6 protocol (placement-free). FAST (per-group, gated by a sound two-round
// shared-L2 test): dual-store h (plain->L2 + sc1->MALL, same addr), plain FL flag after
// vmcnt(1) (local release never waits on MALL), sc0 self h loads, deferred FC=t cross publish.
// Consumers use the SAME FC targets in both modes (t+1 readiness, t-7 back-pressure).
__global__ void __launch_bounds__(256) rnn_kernel(const int* __restrict__ xseq,
                           const float* __restrict__ bias, const float* __restrict__ bias_n,
                           const float* __restrict__ b_out, float* __restrict__ out,
                           char* __restrict__ ws) {
  int* FC = (int*)(ws + OFF_READY);
  int* FL = (int*)(ws + OFF_FL);
  f16* hring = (f16*)(ws + OFF_HRING);                // [3][8][2][64][64][8] transposed
  const int wg = blockIdx.x;
  const int tid = threadIdx.x;
  const int lane = tid & 63, wv = tid >> 6;
  const int quad = lane >> 4, nlane = lane & 15;
  const int xcd = wg & 7, mem = wg >> 3;

  __shared__ __align__(16) f16 wlds[65536];           // 131,072 B
  __shared__ __align__(16) f16 wolds[8192];           // 16,384 B
  __shared__ __align__(16) f16 hstage[64*24];         // 3,072 B
  __shared__ int s_fast, s_bail;

  if (xcd < 6) {
    const int gid = xcd, l = gid >> 1, bh = gid & 1, g = mem;
    {
      const f16x8* src = (const f16x8*)((const f16*)(ws + OFF_WPACK) + ((size_t)(l*32+g) << 16));
      f16x8* dst = (f16x8*)wlds;
      for (int i = tid; i < 8192; i += 256) dst[i] = src[i];
    }
    const int j = g*16 + nlane;
    const float br  = bias[l*1536 + j];
    const float bz  = bias[l*1536 + 512 + j];
    const float bin = bias[l*1536 + 1024 + j];
    const float bn  = bias_n[l*512 + j];
    const int bm = bh*64 + wv*16 + nlane;
    const int tofs = quad*512 + (wv*16 + nlane)*8;    // + kc*2048 per kc

    const int fi = l*64 + bh*32;                      // flag base index for this group
    const int* selfFCp = FC + (fi + (lane & 31))*FPAD;
    const int* selfFLp = FL + (fi + (lane & 31))*FPAD;
    const int* upp = (l > 0) ? (FC + ((l-1)*64 + bh*32 + (lane & 31))*FPAD) : FC;
    const int* bpp = FC; int bpact = 0;
    if (wv == 1) {
      if (l < 2) { if (lane < 32) { bpp = FC + ((l+1)*64 + bh*32 + lane)*FPAD; bpact = 1; } }
      else       { if (lane < 10) { bpp = FC + (192 + bh*10 + lane)*FPAD;      bpact = 1; } }
    }

    // ---- startup: sound shared-L2 test (two rounds; round B rewrites cached lines) ----
    if (tid == 0) {
      int* TS = (int*)(ws + OFF_CTL) + gid*64;        // [64] ints (two 64B lines + pad)
      int* VT = (int*)(ws + OFF_CTL) + 6*64 + gid*32;
      int* MD = (int*)(ws + OFF_CTL) + 6*64 + 6*32;
      int ok = 1;
      // round A: arrival + first visibility (accept A- or B-phase values from fast members)
      st4_pl(TS + g, 100 + g);
      {
        int spins = 0;
        while (1) {
          int good = 1;
          for (int m = 0; m < 32; ++m) {
            int v = ld4_l2(TS + m);
            if (v != 100 + m && v != 200 + m) { good = 0; break; }
          }
          if (good) break;
          if (++spins > (1 << 10)) { ok = 0; break; }
          __builtin_amdgcn_s_sleep(2);
        }
      }
      // round B: REWRITE the same (now cached) lines — only a truly shared L2 shows updates
      if (ok) {
        st4_pl(TS + g, 200 + g);
        int spins = 0;
        while (1) {
          int good = 1;
          for (int m = 0; m < 32; ++m) { if (ld4_l2(TS + m) != 200 + m) { good = 0; break; } }
          if (good) break;
          if (++spins > (1 << 10)) { ok = 0; break; }
          __builtin_amdgcn_s_sleep(2);
        }
      }
      st4_sc1((int*)VT + g, 1 + ok);
      int fast = 0;
      if (g == 0) {                                   // single decider -> consistent group mode
        int spins = 0, allf;
        while (1) {
          int seen = 1; allf = 1;
          for (int m = 0; m < 32; ++m) {
            int v = ld4_sc(VT + m);
            if (v == 0) { seen = 0; break; }
            if (v != 2) allf = 0;
          }
          if (seen) break;
          if (++spins > (1 << 9)) { allf = 0; break; }
          __builtin_amdgcn_s_sleep(4);
        }
        fast = allf;
        st4_sc1(MD + gid, 1 + fast);
      } else {
        int spins = 0;
        while (1) {
          int v = ld4_sc(MD + gid);
          if (v != 0) { fast = (v == 2); break; }
          if (++spins > (1 << 16)) { fast = 0; break; }
          __builtin_amdgcn_s_sleep(8);
        }
      }
      s_fast = fast; s_bail = 0;
    }
    __syncthreads();                                  // also covers wlds staging
    const int fast = s_fast;

    f16x8 wr[32], wz[32];
#pragma unroll
    for (int kc = 0; kc < 32; ++kc) {
      wr[kc] = *(const f16x8*)(wlds + (((0*32 + kc)*64 + lane) << 3));
      wz[kc] = *(const f16x8*)(wlds + (((1*32 + kc)*64 + lane) << 3));
    }
    const f16* embh = (const f16*)(ws + OFF_EMB);
    unsigned short hprev[4] = {0, 0, 0, 0};

    for (int t = 0; t < T_STEPS; ++t) {
      // ---- phase A: upstream readiness + back-pressure (always MALL flags) ----
      if (wv == 0) {
        if (l > 0 && lane >= 32) {
          const int tgt = t + 1;                      // FC_up >= t+1 in BOTH modes
          const int cap = s_bail ? (1<<8) : (1<<22);
          int spins = 0;
          while (1) {
            int v = __hip_atomic_load(upp, __ATOMIC_RELAXED, __HIP_MEMORY_SCOPE_AGENT);
            if (__all(v >= tgt)) break;
            if (++spins > cap) { s_bail = 1; break; }
            __builtin_amdgcn_s_sleep(1);
          }
        }
      } else if (wv == 1) {
        const int tgt = t - (DRING-1);                // conservative for both modes
        const int cap = s_bail ? (1<<8) : (1<<22);
        int spins = 0;
        while (1) {
          int v = 0x7FFFFFFF;
          if (bpact) v = __hip_atomic_load(bpp, __ATOMIC_RELAXED, __HIP_MEMORY_SCOPE_AGENT);
          if (__all(v >= tgt)) break;
          if (++spins > cap) { s_bail = 1; break; }
          __builtin_amdgcn_s_sleep(1);
        }
      }
      __syncthreads();                                // B1: x-input ready

      const int slot_w = t & (DRING-1), slot_r = (t + DRING - 1) & (DRING-1);
      f16x8 afr[32];
      if (l == 0) {
        int idx = xseq[bm*T_STEPS + t];
        const f16* xr = embh + (size_t)idx*HID + quad*8;
#pragma unroll
        for (int kc = 0; kc < 16; ++kc) afr[kc] = ld16_pl(xr + kc*32);
      } else {
        const f16* xr = hring + (size_t)(((l-1)*DRING + slot_w)*2 + bh)*HHALF + tofs;
#pragma unroll
        for (int kc = 0; kc < 16; ++kc) afr[kc] = ld16_sc(xr + kc*2048);
      }
      // ---- phase B: self h(t-1) readiness (FAST: local flags via shared L2) ----
      if (wv == 0 && lane < 32) {
        if (fast) {
          const int cap = s_bail ? (1<<8) : (1<<18);
          int spins = 0;
          while (1) {
            int v = ld4_l2(selfFLp);
            if (__all(v >= t)) break;
            if (++spins > cap) { s_bail = 1; break; }
            __builtin_amdgcn_s_sleep(1);
          }
        } else {
          const int cap = s_bail ? (1<<8) : (1<<22);
          int spins = 0;
          while (1) {
            int v = __hip_atomic_load(selfFCp, __ATOMIC_RELAXED, __HIP_MEMORY_SCOPE_AGENT);
            if (__all(v >= t)) break;
            if (++spins > cap) { s_bail = 1; break; }
            __builtin_amdgcn_s_sleep(1);
          }
        }
      }
      __syncthreads();                                // B2: self h(t-1) visible
      {
        const f16* hrk = hring + (size_t)((l*DRING + slot_r)*2 + bh)*HHALF + tofs;
        if (fast) {
#pragma unroll
          for (int kc = 0; kc < 16; ++kc) afr[16 + kc] = ld16_l2(hrk + kc*2048);
        } else {
#pragma unroll
          for (int kc = 0; kc < 16; ++kc) afr[16 + kc] = ld16_sc(hrk + kc*2048);
        }
      }

      f32x4 ar{0,0,0,0}, az{0,0,0,0}, anxh{0,0,0,0}, anxl{0,0,0,0}, anhh{0,0,0,0}, anhl{0,0,0,0};
      XCHUNK(0, 28)  XCHUNK(4, 24)  XCHUNK(8, 20)   XCHUNK(12, 16)
      HCHUNK(16, 12) HCHUNK(20, 8)  HCHUNK(24, 4)   HCHUNK(28, 0)

#pragma unroll
      for (int i = 0; i < 4; ++i) {
        float rr = sigmoidf_(ar[i] + br);
        float zz = sigmoidf_(az[i] + bz);
        float hn = anhh[i] + anhl[i]*(1.0f/2048.0f) + bn;
        float nn = tanhf_(anxh[i] + anxl[i]*(1.0f/2048.0f) + bin + rr*hn);
        union { unsigned short u; f16 h; } cr; cr.u = hprev[i];
        float hv = nn + zz*((float)cr.h - nn);
        union { f16 h; unsigned short u; } cw; cw.h = (f16)hv;
        hprev[i] = cw.u;
        hstage[(wv*16 + quad*4 + i)*24 + nlane] = cw.h;
      }
      __syncthreads();                                // B3: stage complete
      // dual h stores by waves 2,3 (keeps pollers' vmcnt clean): plain (L2) + sc1 (MALL)
      if (tid >= 128) {
        int ts2 = tid - 128, d8i = ts2 >> 6, row = ts2 & 63;
        f16x8 v8 = *(const f16x8*)(hstage + row*24 + d8i*8);
        f16* hw = hring + (size_t)((l*DRING + slot_w)*2 + bh)*HHALF
                        + (size_t)(2*g + d8i)*512 + row*8;
        if (fast) { st16_pl(hw, v8); st16_sc1(hw, v8);
                    asm volatile("s_waitcnt vmcnt(1)" ::: "memory"); }  // plain retired; sc1 flying
        else      { st16_sc1(hw, v8);
                    asm volatile("s_waitcnt vmcnt(0)" ::: "memory"); }
      }
      __syncthreads();                                // B4
      if (tid == 128) {
        if (fast) { st4_pl (FL + (fi + g)*FPAD, t + 1);       // local release (L2 only)
                    st4_sc1(FC + (fi + g)*FPAD, t); }         // deferred: h(t-1) at MALL
        else      { st4_sc1(FC + (fi + g)*FPAD, t + 1); }     // r6: h(t) at MALL
      }
    }
    // final drain + publish so consumers of h(1023) aren't starved by the FAST deferral
    if (tid >= 128) asm volatile("s_waitcnt vmcnt(0)" ::: "memory");
    __syncthreads();
    if (tid == 128) st4_sc1(FC + (fi + g)*FPAD, T_STEPS);
  } else if (xcd == 6 && mem < 20) {
    const int p = mem, bt = p / 5, vt = p % 5, half = bt >> 1;
    {
      const f16x8* src = (const f16x8*)((const f16*)(ws + OFF_WOUT) + vt*8192);
      f16x8* dst = (f16x8*)wolds;
      for (int i = tid; i < 1024; i += 256) dst[i] = src[i];
    }
    const int v = vt*16 + nlane;
    const float bo = (v < VOC) ? b_out[v] : 0.0f;
    if (tid == 0) s_bail = 0;
    __syncthreads();
    for (int t = 0; t < T_STEPS; ++t) {
      if (wv == 0) {
        const int tgt = t + 1;                        // FC_l2 >= t+1 in BOTH modes
        const int cap = s_bail ? (1<<8) : (1<<22);
        int spins = 0;
        while (1) {
          int vv = 0x7FFFFFFF;
          if (lane < 32) vv = __hip_atomic_load((int*)(ws + OFF_READY) + (2*64 + half*32 + lane)*FPAD,
                                                __ATOMIC_RELAXED, __HIP_MEMORY_SCOPE_AGENT);
          if (__all(vv >= tgt)) break;
          if (++spins > cap) { s_bail = 1; break; }
          __builtin_amdgcn_s_sleep(1);
        }
      }
      __syncthreads();
      if (wv < 2) {
        const int row_abs = bt*32 + wv*16 + nlane;
        const int bh2 = row_abs >> 6, rih = row_abs & 63;
        const f16* hrow = hring + (size_t)((2*DRING + (t & (DRING-1)))*2 + bh2)*HHALF
                                + quad*512 + rih*8;
        f16x8 af[16];
#pragma unroll
        for (int kc = 0; kc < 16; ++kc) af[kc] = ld16_sc(hrow + kc*2048);
        asm volatile("s_waitcnt vmcnt(0)" ::: "memory");
#pragma unroll
        for (int kc = 0; kc < 16; ++kc) asm volatile("" : "+v"(af[kc]));
        f32x4 acc{0,0,0,0};
#pragma unroll
        for (int kc = 0; kc < 16; ++kc) {
          f16x8 w = *(const f16x8*)(wolds + ((kc*64 + lane) << 3));
          acc = __builtin_amdgcn_mfma_f32_16x16x32_f16(af[kc], w, acc, 0, 0, 0);
        }
        if (v < VOC) {
          const int bmb = bt*32 + wv*16;
#pragma unroll
          for (int i = 0; i < 4; ++i) {
            int bidx = bmb + quad*4 + i;
            out[((size_t)bidx*T_STEPS + t)*VOC + v] = acc[i] + bo;
          }
        }
      }
      __syncthreads();
      if (tid == 0)
        st4_sc1((int*)(ws + OFF_READY) + (192 + p)*FPAD, t + 1);
    }
  }
}

extern "C" void kernel_launch(void* const* d_in, const int* in_sizes, int n_in,
                              void* d_out, int out_size, void* d_ws, size_t ws_size,
                              hipStream_t stream) {
  const int*   xseq  = (const int*)d_in[0];
  const float* emb   = (const float*)d_in[1];
  const float* w_ih  = (const float*)d_in[2];
  const float* w_hh  = (const float*)d_in[3];
  const float* b     = (const float*)d_in[4];
  const float* b_n   = (const float*)d_in[5];
  const float* w_out = (const float*)d_in[6];
  const float* b_out = (const float*)d_in[7];
  char* ws = (char*)d_ws;

  // zero flags/ctl + h ring (h[-1] = 0 initial state); re-done every call
  (void)hipMemsetAsync(d_ws, 0, OFF_HRING + HRING_BYTES, stream);
  hipLaunchKernelGGL(convert_kernel, dim3(4096), dim3(256), 0, stream,
                     emb, w_ih, w_hh, w_out, ws);
  hipLaunchKernelGGL(rnn_kernel, dim3(256), dim3(256), 0, stream,
                     xseq, b, b_n, b_out, (float*)d_out, ws);
}